// Round 1
// baseline (393.118 us; speedup 1.0000x reference)
//
#include <hip/hip_runtime.h>
#include <hip/hip_bf16.h>
#include <cstdint>

// Problem dims (fixed by reference setup_inputs)
constexpr int Bc  = 2;
constexpr int Lc  = 4096;
constexpr int Hc  = 2048;
constexpr int LKc = 128;
constexpr float LAMc = 0.003f;

typedef __attribute__((ext_vector_type(8))) __bf16 bf16x8;
typedef __attribute__((ext_vector_type(4))) float  f32x4;

// ---------------------------------------------------------------------------
// async global->LDS, 16B per lane. LDS dest is wave-uniform base + lane*16.
// CK-style addrspace casts via uintptr_t round-trip.
// ---------------------------------------------------------------------------
__device__ __forceinline__ void gl_lds16(const void* g, void* lds) {
  __builtin_amdgcn_global_load_lds(
      (const __attribute__((address_space(1))) uint32_t*)(uintptr_t)g,
      (__attribute__((address_space(3))) uint32_t*)(uint32_t)(uintptr_t)lds,
      16, 0, 0);
}

// ---------------------------------------------------------------------------
// Kernel 1: squash taps + transpose to kq_t[j*H + h]
// k = relu(|k| - lam) * sign(k);  input kernel is [1, H, LK] row-major
// ---------------------------------------------------------------------------
__global__ __launch_bounds__(256) void squash_kernel(
    const float* __restrict__ kin, float* __restrict__ kq) {
  const int idx = blockIdx.x * 256 + threadIdx.x;  // idx = j*H + h
  const int j = idx >> 11;          // / 2048
  const int h = idx & (Hc - 1);
  const float v = kin[h * LKc + j];
  const float a = fabsf(v) - LAMc;
  kq[idx] = (a > 0.f) ? copysignf(a, v) : 0.f;
}

// ---------------------------------------------------------------------------
// Kernel 2: W fp32 [2H, H] -> bf16 same layout
// ---------------------------------------------------------------------------
__global__ __launch_bounds__(256) void wcast_kernel(
    const float* __restrict__ W, __hip_bfloat16* __restrict__ Wb) {
  const int idx = (blockIdx.x * 256 + threadIdx.x) * 4;
  const float4 v = *(const float4*)(W + idx);
  Wb[idx + 0] = __float2bfloat16(v.x);
  Wb[idx + 1] = __float2bfloat16(v.y);
  Wb[idx + 2] = __float2bfloat16(v.z);
  Wb[idx + 3] = __float2bfloat16(v.w);
}

// ---------------------------------------------------------------------------
// Kernel 3: causal 128-tap FIR along L + 2*D*u skip + exact GELU -> bf16 A[M,H]
// Per thread: 16 consecutive l outputs for one h, register sliding window.
//   out[i] += t[127-8c-d] * win[i+d],  win[x] = u[l0-127+8c+x]
// ---------------------------------------------------------------------------
template <bool CHECK>
__device__ __forceinline__ void conv_accum(
    const float* __restrict__ ub, const float* __restrict__ kq,
    const int h, const int l0, float acc[16], float win[23]) {
#pragma unroll
  for (int x = 0; x < 23; ++x) {
    const int il = l0 - 127 + x;
    win[x] = (!CHECK || il >= 0) ? ub[(size_t)il * Hc] : 0.f;
  }
#pragma unroll 4
  for (int c = 0; c < 15; ++c) {
    float t[8];
#pragma unroll
    for (int d = 0; d < 8; ++d) t[d] = kq[(127 - 8 * c - d) * Hc + h];
#pragma unroll
    for (int d = 0; d < 8; ++d)
#pragma unroll
      for (int i = 0; i < 16; ++i)
        acc[i] = fmaf(t[d], win[i + d], acc[i]);
    // shift window by 8, load 8 new
#pragma unroll
    for (int x = 0; x < 15; ++x) win[x] = win[x + 8];
#pragma unroll
    for (int x = 15; x < 23; ++x) {
      const int il = l0 - 127 + 8 * (c + 1) + x;
      win[x] = (!CHECK || il >= 0) ? ub[(size_t)il * Hc] : 0.f;
    }
  }
  {  // c = 15: taps j = 7-d; window now u[l0-7 .. l0+15]
    float t[8];
#pragma unroll
    for (int d = 0; d < 8; ++d) t[d] = kq[(7 - d) * Hc + h];
#pragma unroll
    for (int d = 0; d < 8; ++d)
#pragma unroll
      for (int i = 0; i < 16; ++i)
        acc[i] = fmaf(t[d], win[i + d], acc[i]);
  }
}

__global__ __launch_bounds__(256) void conv_gelu_kernel(
    const float* __restrict__ u, const float* __restrict__ kq,
    const float* __restrict__ Dp, __hip_bfloat16* __restrict__ Aout) {
  const int lane = threadIdx.x & 63;
  const int wv   = threadIdx.x >> 6;
  const int h  = blockIdx.y * 64 + lane;
  const int l0 = blockIdx.x * 64 + wv * 16;
  const int b  = blockIdx.z;
  const float* ub = u + (size_t)b * Lc * Hc + h;

  float acc[16], win[23];
#pragma unroll
  for (int i = 0; i < 16; ++i) acc[i] = 0.f;

  if (blockIdx.x >= 2)
    conv_accum<false>(ub, kq, h, l0, acc, win);
  else
    conv_accum<true>(ub, kq, h, l0, acc, win);

  const float dv = 2.f * Dp[h];  // duplicated skip line in reference -> factor 2
  const size_t obase = ((size_t)b * Lc + l0) * (size_t)Hc + h;
#pragma unroll
  for (int i = 0; i < 16; ++i) {
    const float y  = fmaf(dv, win[i + 7], acc[i]);  // win[i+7] == u[l0+i]
    const float ge = 0.5f * y * (1.f + erff(y * 0.70710678118654752f));
    Aout[obase + (size_t)i * Hc] = __float2bfloat16(ge);
  }
}

// ---------------------------------------------------------------------------
// Kernel 4: GEMM + bias + GLU.
// C_a[m,n] = sum_k A[m,k] Wb[n,k];  C_g[m,n] = sum_k A[m,k] Wb[H+n,k]
// out[m,n] = (C_a + b[n]) * sigmoid(C_g + b[H+n])
// Block: 128 m x 64 n, 256 threads (4 waves), BK=32, 16x16x32 bf16 MFMA.
// ---------------------------------------------------------------------------
__global__ __launch_bounds__(256, 2) void gemm_glu_kernel(
    const __hip_bfloat16* __restrict__ A, const __hip_bfloat16* __restrict__ Wb,
    const float* __restrict__ bias, float* __restrict__ out) {
  __shared__ __align__(16) __hip_bfloat16 As[128 * 32];  // 8 KB
  __shared__ __align__(16) __hip_bfloat16 Bs[128 * 32];  // rows 0..63 = a, 64..127 = g

  const int t    = threadIdx.x;
  const int lane = t & 63;
  const int wv   = t >> 6;
  const int quad = lane >> 4;
  const int l16  = lane & 15;
  const int m0 = blockIdx.x * 128;
  const int n0 = blockIdx.y * 64;

  f32x4 accA[2][4], accG[2][4];
#pragma unroll
  for (int i = 0; i < 2; ++i)
#pragma unroll
    for (int j = 0; j < 4; ++j) {
      accA[i][j] = f32x4{0.f, 0.f, 0.f, 0.f};
      accG[i][j] = f32x4{0.f, 0.f, 0.f, 0.f};
    }

  // staging: thread t covers 16B at linear byte offset t*16 of each 4KB region
  const int srow = t >> 2;         // 0..63
  const int scol = (t & 3) * 8;    // bf16 elements
  const __hip_bfloat16* gA0 = A  + (size_t)(m0 + srow) * Hc + scol;
  const __hip_bfloat16* gA1 = A  + (size_t)(m0 + 64 + srow) * Hc + scol;
  const __hip_bfloat16* gBa = Wb + (size_t)(n0 + srow) * Hc + scol;
  const __hip_bfloat16* gBg = Wb + (size_t)(Hc + n0 + srow) * Hc + scol;
  char* ldsA0 = (char*)As + wv * 1024;
  char* ldsA1 = (char*)As + 4096 + wv * 1024;
  char* ldsBa = (char*)Bs + wv * 1024;
  char* ldsBg = (char*)Bs + 4096 + wv * 1024;

  // fragment read addresses (verified gfx950 layouts):
  // A-frag: A[m = lane&15][k = quad*8 + j]; B-frag: B^T[n = lane&15][k = quad*8 + j]
  const bf16x8* ar0 = (const bf16x8*)(As + (wv * 32 + l16) * 32 + quad * 8);
  const bf16x8* ar1 = (const bf16x8*)(As + (wv * 32 + 16 + l16) * 32 + quad * 8);

  for (int it = 0; it < 64; ++it) {
    const int k0 = it * 32;
    gl_lds16(gA0 + k0, ldsA0);
    gl_lds16(gA1 + k0, ldsA1);
    gl_lds16(gBa + k0, ldsBa);
    gl_lds16(gBg + k0, ldsBg);
    __syncthreads();  // drains vmcnt before barrier (compiler-inserted)
    const bf16x8 af0 = *ar0;
    const bf16x8 af1 = *ar1;
#pragma unroll
    for (int nj = 0; nj < 4; ++nj) {
      const bf16x8 ba = *(const bf16x8*)(Bs + (nj * 16 + l16) * 32 + quad * 8);
      const bf16x8 bg = *(const bf16x8*)(Bs + (64 + nj * 16 + l16) * 32 + quad * 8);
      accA[0][nj] = __builtin_amdgcn_mfma_f32_16x16x32_bf16(af0, ba, accA[0][nj], 0, 0, 0);
      accA[1][nj] = __builtin_amdgcn_mfma_f32_16x16x32_bf16(af1, ba, accA[1][nj], 0, 0, 0);
      accG[0][nj] = __builtin_amdgcn_mfma_f32_16x16x32_bf16(af0, bg, accG[0][nj], 0, 0, 0);
      accG[1][nj] = __builtin_amdgcn_mfma_f32_16x16x32_bf16(af1, bg, accG[1][nj], 0, 0, 0);
    }
    __syncthreads();
  }

  // epilogue: C/D layout col = lane&15, row = quad*4 + reg
  const int mbase = m0 + wv * 32;
#pragma unroll
  for (int mi = 0; mi < 2; ++mi) {
#pragma unroll
    for (int nj = 0; nj < 4; ++nj) {
      const int n = n0 + nj * 16 + l16;
      const float ba_ = bias[n];
      const float bg_ = bias[Hc + n];
#pragma unroll
      for (int r = 0; r < 4; ++r) {
        const int m = mbase + mi * 16 + quad * 4 + r;
        const float a = accA[mi][nj][r] + ba_;
        const float g = accG[mi][nj][r] + bg_;
        out[(size_t)m * Hc + n] = a * (1.f / (1.f + expf(-g)));
      }
    }
  }
}

// ---------------------------------------------------------------------------
extern "C" void kernel_launch(void* const* d_in, const int* in_sizes, int n_in,
                              void* d_out, int out_size, void* d_ws, size_t ws_size,
                              hipStream_t stream) {
  const float* u    = (const float*)d_in[0];  // [B, L, H]
  const float* kin  = (const float*)d_in[1];  // [1, H, LK]
  const float* Dp   = (const float*)d_in[2];  // [1, H]
  const float* W    = (const float*)d_in[3];  // [2H, H]
  const float* bias = (const float*)d_in[4];  // [2H]
  float* out = (float*)d_out;                 // [B, L, H]

  char* ws = (char*)d_ws;
  float*          kq = (float*)ws;                            // LK*H fp32 = 1 MB
  __hip_bfloat16* Wb = (__hip_bfloat16*)(ws + (1 << 20));     // 2H*H bf16 = 16 MB
  __hip_bfloat16* Am = (__hip_bfloat16*)(ws + (17 << 20));    // M*H bf16 = 32 MB

  squash_kernel<<<(Hc * LKc) / 256, 256, 0, stream>>>(kin, kq);
  wcast_kernel<<<(2 * Hc * Hc) / 1024, 256, 0, stream>>>(W, Wb);
  conv_gelu_kernel<<<dim3(Lc / 64, Hc / 64, Bc), 256, 0, stream>>>(u, kq, Dp, Am);
  gemm_glu_kernel<<<dim3((Bc * Lc) / 128, Hc / 64), 256, 0, stream>>>(Am, Wb, bias, out);
}